// Round 2
// baseline (101.002 us; speedup 1.0000x reference)
//
#include <hip/hip_runtime.h>
#include <hip/hip_bf16.h>
#include <stdint.h>
#include <stddef.h>

#define NSEQ  4096
#define DM    1024
#define NHEAD 16
#define DHEAD 64
#define WIN   64
#define K_QKV 1024

using short8 = __attribute__((ext_vector_type(8))) short;
using f32x4  = __attribute__((ext_vector_type(4))) float;

#define GLOBAL_AS __attribute__((address_space(1)))
#define LDS_AS    __attribute__((address_space(3)))

__device__ __forceinline__ unsigned short f2bf(float f) {
  union { float f; unsigned int u; } v; v.f = f;
  unsigned int r = v.u + 0x7FFFu + ((v.u >> 16) & 1u);
  return (unsigned short)(r >> 16);
}

__device__ __forceinline__ void gload_lds16(void* lds, const void* g) {
  __builtin_amdgcn_global_load_lds((const GLOBAL_AS unsigned int*)g,
                                   (LDS_AS unsigned int*)lds, 16, 0, 0);
}

// ---------------- fp32 -> bf16 conversion (vectorized) ----------------
__global__ void cvt_kernel(const float* __restrict__ src,
                           unsigned short* __restrict__ dst, int n4) {
  int i = blockIdx.x * blockDim.x + threadIdx.x;
  if (i < n4) {
    float4 f = ((const float4*)src)[i];
    ushort4 o;
    o.x = f2bf(f.x); o.y = f2bf(f.y); o.z = f2bf(f.z); o.w = f2bf(f.w);
    ((ushort4*)dst)[i] = o;
  }
}

// ================= QKV GEMM: 256x256 tile, BK=32, 8-phase counted-vmcnt ====
// A[M=4096,K=1024], B[N=3072,K=1024] bf16 K-major. 512 thr = 8 waves (2Mx4N),
// per-wave C = 128x64. LDS: 12 half-tile slots x 8KB (3 K-tile buffers),
// subtile-major (16x32 bf16) with st_16x32 XOR swizzle applied by
// pre-swizzling the GLOBAL source address (gload_lds dest stays linear).
// Pipeline: stage 1 half-tile/phase, 2 K-tiles ahead; vmcnt(4) once/K-tile.
__global__ __launch_bounds__(512, 2)
void gemm_qkv8(const unsigned short* __restrict__ A,
               const unsigned short* __restrict__ B,
               const float* __restrict__ bias,
               unsigned short* __restrict__ qo,
               unsigned short* __restrict__ ko,
               unsigned short* __restrict__ vo) {
  __shared__ short lds[12 * 4096];   // 96 KB

  const int bm = blockIdx.x / 12;    // N/256 = 12
  const int bn = blockIdx.x % 12;
  const int m0 = bm << 8, n0 = bn << 8;
  const int tid = threadIdx.x, w = tid >> 6, l = tid & 63;
  const int wr = w >> 2, wc = w & 3;
  const int l15 = l & 15, l4 = l >> 4;

  // staging invariants: wave w writes subtile sr=w of the half (1024B, lane*16)
  const int srow = (w << 4) + (l >> 2);                  // row within 128-half
  const int skel = ((l & 3) << 3) ^ ((l >= 32) << 4);    // k elem (inv-swizzled)
  const int sdst = (w << 9) + (l << 3);                  // shorts within slot

  f32x4 acc[8][4] = {};

  auto stage = [&](int s, int slot) {   // s = global half index (4 per K-tile)
    const int h = s & 3, t = s >> 2;
    const unsigned short* src;
    if (h < 2) src = A + (size_t)(m0 + (h << 7) + srow) * K_QKV + (t << 5) + skel;
    else       src = B + (size_t)(n0 + ((h & 1) << 7) + srow) * K_QKV + (t << 5) + skel;
    gload_lds16(&lds[slot * 4096 + sdst], src);
  };

  // prologue: stage K-tiles 0,1 (halves 0..7 -> slots 0..7)
#pragma unroll
  for (int s = 0; s < 8; ++s) stage(s, s);
  asm volatile("s_waitcnt vmcnt(4)" ::: "memory");   // tile 0 landed
  asm volatile("s_barrier" ::: "memory");

  const int NT = K_QKV / 32;   // 32 K-tiles
  int bufC = 0;                // t % 3
  for (int t = 0; t < NT; ++t) {
    const int sbase = 4 * t + 8;                        // halves of tile t+2
    const int slotb = (bufC == 0 ? 2 : bufC - 1) * 4;   // ((t+2)%3)*4
    const short* At = &lds[(bufC * 4 + wr) * 4096];
    const short* Bt = &lds[(bufC * 4 + 2 + (wc >> 1)) * 4096];
    const int bn0 = (wc & 1) << 6;                      // n offset within half
    short8 af[4], bf[2];
#pragma unroll
    for (int q = 0; q < 4; ++q) {
      const int qa = q >> 1, qb = q & 1;
      if (qb == 0) {
#pragma unroll
        for (int mi = 0; mi < 4; ++mi) {
          const int sr = qa * 4 + mi;
          af[mi] = *(const short8*)&At[sr * 512 + l15 * 32 + ((l4 * 8) ^ ((l15 >= 8) * 16))];
        }
      }
#pragma unroll
      for (int ni = 0; ni < 2; ++ni) {
        const int sr = (bn0 >> 4) + qb * 2 + ni;
        bf[ni] = *(const short8*)&Bt[sr * 512 + l15 * 32 + ((l4 * 8) ^ ((l15 >= 8) * 16))];
      }
      if (t < NT - 2) stage(sbase + q, slotb + q);
      if (q == 3) {
        if (t < NT - 2)      asm volatile("s_waitcnt vmcnt(4)" ::: "memory");
        else if (t == NT - 2) asm volatile("s_waitcnt vmcnt(0)" ::: "memory");
      }
      asm volatile("s_barrier" ::: "memory");
      __builtin_amdgcn_s_setprio(1);
#pragma unroll
      for (int mi = 0; mi < 4; ++mi)
#pragma unroll
        for (int ni = 0; ni < 2; ++ni)
          acc[qa * 4 + mi][qb * 2 + ni] = __builtin_amdgcn_mfma_f32_16x16x32_bf16(
              af[mi], bf[ni], acc[qa * 4 + mi][qb * 2 + ni], 0, 0, 0);
      __builtin_amdgcn_s_setprio(0);
      asm volatile("s_barrier" ::: "memory");
    }
    bufC = bufC == 2 ? 0 : bufC + 1;
  }

  // epilogue: scatter to Q (scaled), K, V^T
#pragma unroll
  for (int ni = 0; ni < 4; ++ni) {
    const int gn = n0 + wc * 64 + ni * 16 + l15;
    const float bv = bias[gn];
    const int region = gn >> 10;   // block-uniform (256-col tiles)
#pragma unroll
    for (int mi = 0; mi < 8; ++mi) {
      const int gm = m0 + wr * 128 + mi * 16 + l4 * 4;
      if (region == 0) {
        const int h = (gn >> 6) & 15, d = gn & 63;
#pragma unroll
        for (int r = 0; r < 4; ++r)
          qo[((size_t)(h * NSEQ + gm + r)) * DHEAD + d] =
              f2bf((acc[mi][ni][r] + bv) * 0.125f);
      } else if (region == 1) {
        const int nn = gn - 1024;
        const int h = nn >> 6, d = nn & 63;
#pragma unroll
        for (int r = 0; r < 4; ++r)
          ko[((size_t)(h * NSEQ + gm + r)) * DHEAD + d] =
              f2bf(acc[mi][ni][r] + bv);
      } else {
        const int nn = gn - 2048;    // = h*64 + d
        ushort4 pk;
        pk.x = f2bf(acc[mi][ni][0] + bv);
        pk.y = f2bf(acc[mi][ni][1] + bv);
        pk.z = f2bf(acc[mi][ni][2] + bv);
        pk.w = f2bf(acc[mi][ni][3] + bv);
        *(ushort4*)&vo[(size_t)nn * NSEQ + gm] = pk;   // V^T: [h*64+d][m]
      }
    }
  }
}

// ---------------- out-proj GEMM: C[M,N] = A[M,K] * B[N,K]^T + bias ---------
// unchanged 128x128 2-phase structure
__global__ __launch_bounds__(256)
void gemm_bt(const unsigned short* __restrict__ A,
             const unsigned short* __restrict__ B,
             const float* __restrict__ bias,
             float* __restrict__ Cf,
             int M, int N, int K) {
  __shared__ short As[2][128 * 32];
  __shared__ short Bs[2][128 * 32];

  const int nbn = N >> 7;
  const int bm  = blockIdx.x / nbn;
  const int bn  = blockIdx.x % nbn;
  const int tid = threadIdx.x;
  const int w   = tid >> 6;
  const int l   = tid & 63;
  const int wr  = w >> 1, wc = w & 1;
  const int l15 = l & 15, l4 = l >> 4;

  const int m0 = bm << 7;
  const int n0 = bn << 7;

  f32x4 acc[4][4] = {};
  const int nkt = K >> 5;

  auto stage = [&](int buf, int kt) {
    const int kbase = kt << 5;
#pragma unroll
    for (int r = 0; r < 2; ++r) {
      const int c   = r * 4 + w;
      const int row = c * 16 + (l >> 2);
      const int ke  = (l & 3) << 3;
      gload_lds16(&As[buf][c * 512 + l * 8],
                  A + (size_t)(m0 + row) * K + kbase + ke);
      gload_lds16(&Bs[buf][c * 512 + l * 8],
                  B + (size_t)(n0 + row) * K + kbase + ke);
    }
  };

  stage(0, 0);
  int cur = 0;
  for (int kt = 0; kt < nkt; ++kt) {
    __syncthreads();
    if (kt + 1 < nkt) stage(cur ^ 1, kt + 1);
    short8 a[4], b[4];
#pragma unroll
    for (int mi = 0; mi < 4; ++mi)
      a[mi] = *(const short8*)&As[cur][(wr * 64 + mi * 16 + l15) * 32 + l4 * 8];
#pragma unroll
    for (int ni = 0; ni < 4; ++ni)
      b[ni] = *(const short8*)&Bs[cur][(wc * 64 + ni * 16 + l15) * 32 + l4 * 8];
#pragma unroll
    for (int mi = 0; mi < 4; ++mi)
#pragma unroll
      for (int ni = 0; ni < 4; ++ni)
        acc[mi][ni] = __builtin_amdgcn_mfma_f32_16x16x32_bf16(a[mi], b[ni], acc[mi][ni], 0, 0, 0);
    cur ^= 1;
  }

#pragma unroll
  for (int ni = 0; ni < 4; ++ni) {
    const int n  = n0 + wc * 64 + ni * 16 + l15;
    const float bv = bias[n];
#pragma unroll
    for (int mi = 0; mi < 4; ++mi) {
      const int mb = m0 + wr * 64 + mi * 16 + l4 * 4;
#pragma unroll
      for (int r = 0; r < 4; ++r)
        Cf[(size_t)(mb + r) * N + n] = acc[mi][ni][r] + bv;
    }
  }
}

// ---------------- windowed causal attention (unchanged) ----------------
__global__ __launch_bounds__(256)
void attn_kernel(const unsigned short* __restrict__ Qb,
                 const unsigned short* __restrict__ Kb,
                 const unsigned short* __restrict__ Vt,
                 unsigned short* __restrict__ att) {
  __shared__ short Pl[4][16][136];
  const int h  = blockIdx.x >> 6;
  const int q0 = (blockIdx.x & 63) << 6;
  const int w  = threadIdx.x >> 6;
  const int l  = threadIdx.x & 63;
  const int l15 = l & 15, l4 = l >> 4;
  const int qw = q0 + w * 16;

  const unsigned short* Qh = Qb + (size_t)h * NSEQ * DHEAD;
  const unsigned short* Kh = Kb + (size_t)h * NSEQ * DHEAD;
  const unsigned short* Vh = Vt + (size_t)h * DHEAD * NSEQ;

  short8 aq[2];
  {
    const int qrow = qw + l15;
    aq[0] = *(const short8*)&Qh[(size_t)qrow * DHEAD + l4 * 8];
    aq[1] = *(const short8*)&Qh[(size_t)qrow * DHEAD + 32 + l4 * 8];
  }

  f32x4 s[8] = {};
#pragma unroll
  for (int t = 0; t < 8; ++t) {
    int j  = q0 - 64 + t * 16 + l15;
    int jc = j < 0 ? 0 : j;
    short8 b0 = *(const short8*)&Kh[(size_t)jc * DHEAD + l4 * 8];
    short8 b1 = *(const short8*)&Kh[(size_t)jc * DHEAD + 32 + l4 * 8];
    s[t] = __builtin_amdgcn_mfma_f32_16x16x32_bf16(aq[0], b0, s[t], 0, 0, 0);
    s[t] = __builtin_amdgcn_mfma_f32_16x16x32_bf16(aq[1], b1, s[t], 0, 0, 0);
  }

  float rmax[4] = {-3e38f, -3e38f, -3e38f, -3e38f};
#pragma unroll
  for (int t = 0; t < 8; ++t)
#pragma unroll
    for (int r = 0; r < 4; ++r) {
      const int i = qw + l4 * 4 + r;
      const int j = q0 - 64 + t * 16 + l15;
      const int diff = i - j;
      float sv = (j >= 0 && diff >= 0 && diff < WIN) ? s[t][r] : -3e38f;
      s[t][r] = sv;
      rmax[r] = fmaxf(rmax[r], sv);
    }
#pragma unroll
  for (int r = 0; r < 4; ++r)
#pragma unroll
    for (int m = 1; m < 16; m <<= 1)
      rmax[r] = fmaxf(rmax[r], __shfl_xor(rmax[r], m, 64));

  float rsum[4] = {0.f, 0.f, 0.f, 0.f};
#pragma unroll
  for (int t = 0; t < 8; ++t)
#pragma unroll
    for (int r = 0; r < 4; ++r) {
      float p = __expf(s[t][r] - rmax[r]);
      s[t][r] = p;
      rsum[r] += p;
    }
#pragma unroll
  for (int r = 0; r < 4; ++r)
#pragma unroll
    for (int m = 1; m < 16; m <<= 1)
      rsum[r] += __shfl_xor(rsum[r], m, 64);

#pragma unroll
  for (int t = 0; t < 8; ++t)
#pragma unroll
    for (int r = 0; r < 4; ++r)
      Pl[w][l4 * 4 + r][t * 16 + l15] = (short)f2bf(s[t][r]);

  f32x4 o[4] = {};
#pragma unroll
  for (int ks = 0; ks < 4; ++ks) {
    short8 ap = *(const short8*)&Pl[w][l15][ks * 32 + l4 * 8];
    int jg = q0 - 64 + ks * 32 + l4 * 8;
    if (jg < 0) jg = 0;
#pragma unroll
    for (int dt = 0; dt < 4; ++dt) {
      const int d = dt * 16 + l15;
      short8 bv = *(const short8*)&Vh[(size_t)d * NSEQ + jg];
      o[dt] = __builtin_amdgcn_mfma_f32_16x16x32_bf16(ap, bv, o[dt], 0, 0, 0);
    }
  }

#pragma unroll
  for (int r = 0; r < 4; ++r) {
    const float rinv = 1.0f / rsum[r];
    const int m = qw + l4 * 4 + r;
#pragma unroll
    for (int dt = 0; dt < 4; ++dt)
      att[(size_t)m * DM + h * DHEAD + dt * 16 + l15] = f2bf(o[dt][r] * rinv);
  }
}

// ---------------- launch ----------------
extern "C" void kernel_launch(void* const* d_in, const int* in_sizes, int n_in,
                              void* d_out, int out_size, void* d_ws, size_t ws_size,
                              hipStream_t stream) {
  const float* x    = (const float*)d_in[0];
  const float* wqkv = (const float*)d_in[1];
  const float* bqkv = (const float*)d_in[2];
  const float* wout = (const float*)d_in[3];
  const float* bout = (const float*)d_in[4];
  float* out = (float*)d_out;

  unsigned short* ws = (unsigned short*)d_ws;
  unsigned short* xb    = ws;
  unsigned short* wqkvb = xb    + (size_t)NSEQ * DM;
  unsigned short* woutb = wqkvb + (size_t)3 * DM * DM;
  unsigned short* qb    = woutb + (size_t)DM * DM;
  unsigned short* kb    = qb    + (size_t)NSEQ * DM;
  unsigned short* vtb   = kb    + (size_t)NSEQ * DM;
  unsigned short* attb  = vtb   + (size_t)NSEQ * DM;

  cvt_kernel<<<(NSEQ * DM / 4 + 255) / 256, 256, 0, stream>>>(x, xb, NSEQ * DM / 4);
  cvt_kernel<<<(3 * DM * DM / 4 + 255) / 256, 256, 0, stream>>>(wqkv, wqkvb, 3 * DM * DM / 4);
  cvt_kernel<<<(DM * DM / 4 + 255) / 256, 256, 0, stream>>>(wout, woutb, DM * DM / 4);

  gemm_qkv8<<<(NSEQ / 256) * (3 * DM / 256), 512, 0, stream>>>(
      xb, wqkvb, bqkv, qb, kb, vtb);

  attn_kernel<<<NHEAD * (NSEQ / 64), 256, 0, stream>>>(qb, kb, vtb, attb);

  gemm_bt<<<(NSEQ / 128) * (DM / 128), 256, 0, stream>>>(
      attb, woutb, bout, out, NSEQ, DM, DM);
}

// Round 3
// 89.582 us; speedup vs baseline: 1.1275x; 1.1275x over previous
//
#include <hip/hip_runtime.h>
#include <hip/hip_bf16.h>
#include <stdint.h>
#include <stddef.h>

#define NSEQ  4096
#define DM    1024
#define NHEAD 16
#define DHEAD 64
#define WIN   64

using short8 = __attribute__((ext_vector_type(8))) short;
using f32x4  = __attribute__((ext_vector_type(4))) float;

#define GLOBAL_AS __attribute__((address_space(1)))
#define LDS_AS    __attribute__((address_space(3)))

__device__ __forceinline__ unsigned short f2bf(float f) {
  union { float f; unsigned int u; } v; v.f = f;
  unsigned int r = v.u + 0x7FFFu + ((v.u >> 16) & 1u);
  return (unsigned short)(r >> 16);
}

__device__ __forceinline__ void gload_lds16(void* lds, const void* g) {
  __builtin_amdgcn_global_load_lds((const GLOBAL_AS unsigned int*)g,
                                   (LDS_AS unsigned int*)lds, 16, 0, 0);
}

// ---------------- fused fp32 -> bf16 conversion (x | w_qkv | w_out) --------
// destinations are contiguous in workspace: xb(1M grp) wqkvb(768K) woutb(256K)
#define NX4 1048576
#define NW4 786432
__global__ void cvt_all(const float* __restrict__ x,
                        const float* __restrict__ wqkv,
                        const float* __restrict__ wout,
                        unsigned short* __restrict__ dst) {
  int i = blockIdx.x * blockDim.x + threadIdx.x;   // group of 4 floats
  float4 f;
  if (i < NX4)            f = ((const float4*)x)[i];
  else if (i < NX4 + NW4) f = ((const float4*)wqkv)[i - NX4];
  else                    f = ((const float4*)wout)[i - (NX4 + NW4)];
  ushort4 o;
  o.x = f2bf(f.x); o.y = f2bf(f.y); o.z = f2bf(f.z); o.w = f2bf(f.w);
  ((ushort4*)dst)[i] = o;
}

// ========== GEMM: C[M,N] = A[M,K]*B[N,K]^T + bias; 128x128, BK=32 ==========
// 4 waves (2x2 of 64x64). Triple-buffered LDS (3 x 16KB), st_16x32 XOR
// swizzle via pre-swizzled global source (linear gload_lds dest).
// One barrier + counted vmcnt(4) per K-tile; 16 MFMA per barrier.
// EPI 0: scatter -> Q (scaled), K, V^T.   EPI 1: fp32 + bias -> Cf.
template<int EPI>
__global__ __launch_bounds__(256)
void gemm3(const unsigned short* __restrict__ A,
           const unsigned short* __restrict__ B,
           const float* __restrict__ bias,
           float* __restrict__ Cf,
           unsigned short* __restrict__ qo,
           unsigned short* __restrict__ ko,
           unsigned short* __restrict__ vo,
           int M, int N, int K) {
  __shared__ short lds[3][8192];   // [buf][A:4096 | B:4096] shorts = 48 KB

  const int nbn = N >> 7;
  const int bm  = blockIdx.x / nbn;
  const int bn  = blockIdx.x % nbn;
  const int m0  = bm << 7, n0 = bn << 7;
  const int tid = threadIdx.x, w = tid >> 6, l = tid & 63;
  const int wr  = w >> 1, wc = w & 1;
  const int l15 = l & 15, l4 = l >> 4;

  // staging: linear LDS dest, inverse-swizzled global k offset (rule #21)
  const int skel = ((l & 3) << 3) ^ ((l >= 32) << 4);
  // fragment read offset within a 16x32 subtile (st_16x32 swizzle)
  const int roff = l15 * 32 + ((l4 * 8) ^ ((l15 >= 8) * 16));

  f32x4 acc[4][4] = {};
  const int NT = K >> 5;

  auto stage = [&](int t) {
    const int buf = t % 3;
    const int kb  = t << 5;
#pragma unroll
    for (int r = 0; r < 2; ++r) {
      const int c   = r * 4 + w;            // 16-row subtile index 0..7
      const int row = c * 16 + (l >> 2);
      gload_lds16(&lds[buf][c * 512 + l * 8],
                  A + (size_t)(m0 + row) * K + kb + skel);
      gload_lds16(&lds[buf][4096 + c * 512 + l * 8],
                  B + (size_t)(n0 + row) * K + kb + skel);
    }
  };

  stage(0);
  stage(1);
  asm volatile("s_waitcnt vmcnt(4)" ::: "memory");   // tile 0 landed
  __builtin_amdgcn_s_barrier();

  for (int t = 0; t < NT; ++t) {
    const short* Ab = &lds[t % 3][0];
    const short* Bb = &lds[t % 3][4096];
    short8 af[4], bf[4];
#pragma unroll
    for (int i = 0; i < 4; ++i) {
      af[i] = *(const short8*)&Ab[(wr * 4 + i) * 512 + roff];
      bf[i] = *(const short8*)&Bb[(wc * 4 + i) * 512 + roff];
    }
    if (t + 2 < NT) stage(t + 2);
    if (t + 2 < NT)       asm volatile("s_waitcnt vmcnt(4)" ::: "memory");
    else if (t + 2 == NT) asm volatile("s_waitcnt vmcnt(0)" ::: "memory");
    __builtin_amdgcn_s_barrier();   // publishes: tile t+1 landed for all waves
    __builtin_amdgcn_s_setprio(1);
#pragma unroll
    for (int mi = 0; mi < 4; ++mi)
#pragma unroll
      for (int ni = 0; ni < 4; ++ni)
        acc[mi][ni] = __builtin_amdgcn_mfma_f32_16x16x32_bf16(
            af[mi], bf[ni], acc[mi][ni], 0, 0, 0);
    __builtin_amdgcn_s_setprio(0);
  }

  if (EPI == 0) {
    // n = (region<<10) + h*64 + d ; region 0=Q,1=K,2=V
#pragma unroll
    for (int ni = 0; ni < 4; ++ni) {
      const int n  = n0 + wc * 64 + ni * 16 + l15;
      const float bv = bias[n];
      const int region = n >> 10;   // block-uniform for 128-col tiles
#pragma unroll
      for (int mi = 0; mi < 4; ++mi) {
        const int mb = m0 + wr * 64 + mi * 16 + l4 * 4;
        if (region == 0) {
          const int h = (n >> 6) & 15, d = n & 63;
#pragma unroll
          for (int r = 0; r < 4; ++r)
            qo[((size_t)(h * NSEQ + mb + r)) * DHEAD + d] =
                f2bf((acc[mi][ni][r] + bv) * 0.125f);
        } else if (region == 1) {
          const int nn = n - 1024;
          const int h = nn >> 6, d = nn & 63;
#pragma unroll
          for (int r = 0; r < 4; ++r)
            ko[((size_t)(h * NSEQ + mb + r)) * DHEAD + d] =
                f2bf(acc[mi][ni][r] + bv);
        } else {
          const int nn = n - 2048;    // = h*64 + d
          ushort4 pk;
          pk.x = f2bf(acc[mi][ni][0] + bv);
          pk.y = f2bf(acc[mi][ni][1] + bv);
          pk.z = f2bf(acc[mi][ni][2] + bv);
          pk.w = f2bf(acc[mi][ni][3] + bv);
          *(ushort4*)&vo[(size_t)nn * NSEQ + mb] = pk;   // V^T: [h*64+d][m]
        }
      }
    }
  } else {
#pragma unroll
    for (int ni = 0; ni < 4; ++ni) {
      const int n  = n0 + wc * 64 + ni * 16 + l15;
      const float bv = bias[n];
#pragma unroll
      for (int mi = 0; mi < 4; ++mi) {
        const int mb = m0 + wr * 64 + mi * 16 + l4 * 4;
#pragma unroll
        for (int r = 0; r < 4; ++r)
          Cf[(size_t)(mb + r) * N + n] = acc[mi][ni][r] + bv;
      }
    }
  }
}

// ---------------- windowed causal attention (unchanged) ----------------
__global__ __launch_bounds__(256)
void attn_kernel(const unsigned short* __restrict__ Qb,
                 const unsigned short* __restrict__ Kb,
                 const unsigned short* __restrict__ Vt,
                 unsigned short* __restrict__ att) {
  __shared__ short Pl[4][16][136];
  const int h  = blockIdx.x >> 6;
  const int q0 = (blockIdx.x & 63) << 6;
  const int w  = threadIdx.x >> 6;
  const int l  = threadIdx.x & 63;
  const int l15 = l & 15, l4 = l >> 4;
  const int qw = q0 + w * 16;

  const unsigned short* Qh = Qb + (size_t)h * NSEQ * DHEAD;
  const unsigned short* Kh = Kb + (size_t)h * NSEQ * DHEAD;
  const unsigned short* Vh = Vt + (size_t)h * DHEAD * NSEQ;

  short8 aq[2];
  {
    const int qrow = qw + l15;
    aq[0] = *(const short8*)&Qh[(size_t)qrow * DHEAD + l4 * 8];
    aq[1] = *(const short8*)&Qh[(size_t)qrow * DHEAD + 32 + l4 * 8];
  }

  f32x4 s[8] = {};
#pragma unroll
  for (int t = 0; t < 8; ++t) {
    int j  = q0 - 64 + t * 16 + l15;
    int jc = j < 0 ? 0 : j;
    short8 b0 = *(const short8*)&Kh[(size_t)jc * DHEAD + l4 * 8];
    short8 b1 = *(const short8*)&Kh[(size_t)jc * DHEAD + 32 + l4 * 8];
    s[t] = __builtin_amdgcn_mfma_f32_16x16x32_bf16(aq[0], b0, s[t], 0, 0, 0);
    s[t] = __builtin_amdgcn_mfma_f32_16x16x32_bf16(aq[1], b1, s[t], 0, 0, 0);
  }

  float rmax[4] = {-3e38f, -3e38f, -3e38f, -3e38f};
#pragma unroll
  for (int t = 0; t < 8; ++t)
#pragma unroll
    for (int r = 0; r < 4; ++r) {
      const int i = qw + l4 * 4 + r;
      const int j = q0 - 64 + t * 16 + l15;
      const int diff = i - j;
      float sv = (j >= 0 && diff >= 0 && diff < WIN) ? s[t][r] : -3e38f;
      s[t][r] = sv;
      rmax[r] = fmaxf(rmax[r], sv);
    }
#pragma unroll
  for (int r = 0; r < 4; ++r)
#pragma unroll
    for (int m = 1; m < 16; m <<= 1)
      rmax[r] = fmaxf(rmax[r], __shfl_xor(rmax[r], m, 64));

  float rsum[4] = {0.f, 0.f, 0.f, 0.f};
#pragma unroll
  for (int t = 0; t < 8; ++t)
#pragma unroll
    for (int r = 0; r < 4; ++r) {
      float p = __expf(s[t][r] - rmax[r]);
      s[t][r] = p;
      rsum[r] += p;
    }
#pragma unroll
  for (int r = 0; r < 4; ++r)
#pragma unroll
    for (int m = 1; m < 16; m <<= 1)
      rsum[r] += __shfl_xor(rsum[r], m, 64);

#pragma unroll
  for (int t = 0; t < 8; ++t)
#pragma unroll
    for (int r = 0; r < 4; ++r)
      Pl[w][l4 * 4 + r][t * 16 + l15] = (short)f2bf(s[t][r]);

  f32x4 o[4] = {};
#pragma unroll
  for (int ks = 0; ks < 4; ++ks) {
    short8 ap = *(const short8*)&Pl[w][l15][ks * 32 + l4 * 8];
    int jg = q0 - 64 + ks * 32 + l4 * 8;
    if (jg < 0) jg = 0;
#pragma unroll
    for (int dt = 0; dt < 4; ++dt) {
      const int d = dt * 16 + l15;
      short8 bv = *(const short8*)&Vh[(size_t)d * NSEQ + jg];
      o[dt] = __builtin_amdgcn_mfma_f32_16x16x32_bf16(ap, bv, o[dt], 0, 0, 0);
    }
  }

#pragma unroll
  for (int r = 0; r < 4; ++r) {
    const float rinv = 1.0f / rsum[r];
    const int m = qw + l4 * 4 + r;
#pragma unroll
    for (int dt = 0; dt < 4; ++dt)
      att[(size_t)m * DM + h * DHEAD + dt * 16 + l15] = f2bf(o[dt][r] * rinv);
  }
}

// ---------------- launch ----------------
extern "C" void kernel_launch(void* const* d_in, const int* in_sizes, int n_in,
                              void* d_out, int out_size, void* d_ws, size_t ws_size,
                              hipStream_t stream) {
  const float* x    = (const float*)d_in[0];
  const float* wqkv = (const float*)d_in[1];
  const float* bqkv = (const float*)d_in[2];
  const float* wout = (const float*)d_in[3];
  const float* bout = (const float*)d_in[4];
  float* out = (float*)d_out;

  unsigned short* ws = (unsigned short*)d_ws;
  unsigned short* xb    = ws;                                  // 4M elems
  unsigned short* wqkvb = xb    + (size_t)NSEQ * DM;           // 3M (contig after xb)
  unsigned short* woutb = wqkvb + (size_t)3 * DM * DM;         // 1M (contig)
  unsigned short* qb    = woutb + (size_t)DM * DM;
  unsigned short* kb    = qb    + (size_t)NSEQ * DM;
  unsigned short* vtb   = kb    + (size_t)NSEQ * DM;
  unsigned short* attb  = vtb   + (size_t)NSEQ * DM;

  cvt_all<<<8192, 256, 0, stream>>>(x, wqkv, wout, xb);

  gemm3<0><<<(NSEQ / 128) * (3 * DM / 128), 256, 0, stream>>>(
      xb, wqkvb, bqkv, nullptr, qb, kb, vtb, NSEQ, 3 * DM, DM);

  attn_kernel<<<NHEAD * (NSEQ / 64), 256, 0, stream>>>(qb, kb, vtb, attb);

  gemm3<1><<<(NSEQ / 128) * (DM / 128), 256, 0, stream>>>(
      attb, woutb, bout, out, nullptr, nullptr, nullptr, NSEQ, DM, DM);
}